// Round 1
// baseline (235.514 us; speedup 1.0000x reference)
//
#include <hip/hip_runtime.h>
#include <math.h>

#define WDIM 160
#define HDIM 160
#define DDIM 160

struct W7 { float w[7]; };

// ---- Pass along W (innermost, stride 1) ----
__global__ void blur_w(const float* __restrict__ in, float* __restrict__ out,
                       W7 wt, int total) {
    int idx = blockIdx.x * blockDim.x + threadIdx.x;
    if (idx >= total) return;
    int w = idx % WDIM;
    float acc = 0.f;
#pragma unroll
    for (int j = 0; j < 7; ++j) {
        int ww = w + j - 3;
        if (ww >= 0 && ww < WDIM) acc += wt.w[j] * in[idx + (j - 3)];
    }
    out[idx] = acc;
}

// ---- Pass along H (stride WDIM) ----
__global__ void blur_h(const float* __restrict__ in, float* __restrict__ out,
                       W7 wt, int total) {
    int idx = blockIdx.x * blockDim.x + threadIdx.x;
    if (idx >= total) return;
    int h = (idx / WDIM) % HDIM;
    float acc = 0.f;
#pragma unroll
    for (int j = 0; j < 7; ++j) {
        int hh = h + j - 3;
        if (hh >= 0 && hh < HDIM) acc += wt.w[j] * in[idx + (j - 3) * WDIM];
    }
    out[idx] = acc;
}

// ---- Pass along D (stride WDIM*HDIM) ----
__global__ void blur_d(const float* __restrict__ in, float* __restrict__ out,
                       W7 wt, int total) {
    int idx = blockIdx.x * blockDim.x + threadIdx.x;
    if (idx >= total) return;
    const int slab = WDIM * HDIM;
    int d = (idx / slab) % DDIM;
    float acc = 0.f;
#pragma unroll
    for (int j = 0; j < 7; ++j) {
        int dd = d + j - 3;
        if (dd >= 0 && dd < DDIM) acc += wt.w[j] * in[idx + (j - 3) * slab];
    }
    out[idx] = acc;
}

// ---- Fallback: direct 343-tap depthwise conv (only if ws too small) ----
__global__ void blur3d_naive(const float* __restrict__ in, float* __restrict__ out,
                             W7 wt, int total) {
    int idx = blockIdx.x * blockDim.x + threadIdx.x;
    if (idx >= total) return;
    int w = idx % WDIM;
    int h = (idx / WDIM) % HDIM;
    int d = (idx / (WDIM * HDIM)) % DDIM;
    const float* base = in + (idx - w - h * WDIM - d * WDIM * HDIM);
    float acc = 0.f;
    for (int a = 0; a < 7; ++a) {
        int dd = d + a - 3;
        if (dd < 0 || dd >= DDIM) continue;
        for (int b = 0; b < 7; ++b) {
            int hh = h + b - 3;
            if (hh < 0 || hh >= HDIM) continue;
            float wab = wt.w[a] * wt.w[b];
            for (int c = 0; c < 7; ++c) {
                int ww = w + c - 3;
                if (ww < 0 || ww >= WDIM) continue;
                acc += wab * wt.w[c] * base[(dd * HDIM + hh) * WDIM + ww];
            }
        }
    }
    out[idx] = acc;
}

extern "C" void kernel_launch(void* const* d_in, const int* in_sizes, int n_in,
                              void* d_out, int out_size, void* d_ws, size_t ws_size,
                              hipStream_t stream) {
    const float* x = (const float*)d_in[0];
    float* out = (float*)d_out;
    const int total = out_size;  // 2*2*160*160*160 = 16,384,000

    // Gaussian weights: exp(-(i-3)^2 / (2*sigma^2)), sigma=2 -> /8, normalized.
    W7 wt;
    double s = 0.0;
    for (int i = 0; i < 7; ++i) {
        double v = exp(-((i - 3) * (i - 3)) / 8.0);
        wt.w[i] = (float)v;
        s += v;
    }
    for (int i = 0; i < 7; ++i) wt.w[i] = (float)(wt.w[i] / s);

    const int threads = 256;
    const int blocks = (total + threads - 1) / threads;

    if (ws_size >= (size_t)total * sizeof(float)) {
        float* tmp = (float*)d_ws;
        // x --W--> out --H--> tmp --D--> out
        blur_w<<<blocks, threads, 0, stream>>>(x, out, wt, total);
        blur_h<<<blocks, threads, 0, stream>>>(out, tmp, wt, total);
        blur_d<<<blocks, threads, 0, stream>>>(tmp, out, wt, total);
    } else {
        blur3d_naive<<<blocks, threads, 0, stream>>>(x, out, wt, total);
    }
}

// Round 2
// 108.268 us; speedup vs baseline: 2.1753x; 2.1753x over previous
//
#include <hip/hip_runtime.h>
#include <math.h>

#define DIM 160
#define HT 16            // h-tile rows per block
#define ROWS (HT + 6)    // 22 rows incl. halo
#define LROW 168         // padded LDS row: 4 zero | 160 data | 4 zero

struct W7 { float w[7]; };

// ---- Fused W+H blur of one (d-slice, h-strip): x -> ws ----
__global__ __launch_bounds__(256) void blur_wh(const float* __restrict__ in,
                                               float* __restrict__ out, W7 wt) {
    __shared__ float inL[ROWS * LROW];   // padded raw rows
    __shared__ float tmpL[ROWS * DIM];   // W-blurred rows

    const int tilesH = DIM / HT;                 // 10
    int b   = blockIdx.x;
    int nc  = b / (DIM * tilesH);
    int rem = b % (DIM * tilesH);
    int d   = rem / tilesH;
    int h0  = (rem % tilesH) * HT;
    int tid = threadIdx.x;

    const float* img = in + ((size_t)nc * DIM + d) * (DIM * DIM);

    // stage 1: load 22 rows (zero outside H range) into padded LDS, float4
    for (int i = tid; i < ROWS * 40; i += 256) {
        int r = i / 40, c = i % 40;
        int h = h0 - 3 + r;
        float4 v = make_float4(0.f, 0.f, 0.f, 0.f);
        if (h >= 0 && h < DIM) v = ((const float4*)(img + h * DIM))[c];
        ((float4*)(inL + r * LROW + 4))[c] = v;
    }
    // zero the guard columns (w-padding => branch-free W loop)
    for (int i = tid; i < ROWS * 2; i += 256) {
        int r = i / 2, side = i % 2;
        ((float4*)(inL + r * LROW + (side ? 164 : 0)))[0] =
            make_float4(0.f, 0.f, 0.f, 0.f);
    }
    __syncthreads();

    // stage 2: W-blur (branch-free thanks to guards)
    for (int i = tid; i < ROWS * DIM; i += 256) {
        int r = i / DIM, w = i % DIM;
        const float* p = inL + r * LROW + w + 1;   // = &in[w-3] in padded coords
        float acc = 0.f;
#pragma unroll
        for (int j = 0; j < 7; ++j) acc += wt.w[j] * p[j];
        tmpL[r * DIM + w] = acc;
    }
    __syncthreads();

    // stage 3: H-blur + float4 store
    float* orow = out + ((size_t)nc * DIM + d) * (DIM * DIM) + (size_t)h0 * DIM;
    for (int i = tid; i < HT * 40; i += 256) {
        int hh = i / 40, c = i % 40;
        float4 acc = make_float4(0.f, 0.f, 0.f, 0.f);
#pragma unroll
        for (int j = 0; j < 7; ++j) {
            float4 t = ((const float4*)(tmpL + (hh + j) * DIM))[c];
            float wj = wt.w[j];
            acc.x += wj * t.x; acc.y += wj * t.y;
            acc.z += wj * t.z; acc.w += wj * t.w;
        }
        ((float4*)(orow + hh * DIM))[c] = acc;
    }
}

// ---- D blur, float4 per thread: ws -> out ----
__global__ __launch_bounds__(256) void blur_d4(const float4* __restrict__ in,
                                               float4* __restrict__ out,
                                               W7 wt, int total4) {
    int idx = blockIdx.x * 256 + threadIdx.x;
    if (idx >= total4) return;
    const int slab4 = DIM * DIM / 4;   // 6400 float4 per d-slice
    int d = (idx / slab4) % DIM;
    float4 acc = make_float4(0.f, 0.f, 0.f, 0.f);
    if (d >= 3 && d <= DIM - 4) {      // wave-uniform fast path
#pragma unroll
        for (int j = 0; j < 7; ++j) {
            float4 v = in[idx + (j - 3) * slab4];
            float wj = wt.w[j];
            acc.x += wj * v.x; acc.y += wj * v.y;
            acc.z += wj * v.z; acc.w += wj * v.w;
        }
    } else {
#pragma unroll
        for (int j = 0; j < 7; ++j) {
            int dd = d + j - 3;
            if (dd >= 0 && dd < DIM) {
                float4 v = in[idx + (j - 3) * slab4];
                float wj = wt.w[j];
                acc.x += wj * v.x; acc.y += wj * v.y;
                acc.z += wj * v.z; acc.w += wj * v.w;
            }
        }
    }
    out[idx] = acc;
}

// ---- Fallback: direct 343-tap (only if ws too small) ----
__global__ void blur3d_naive(const float* __restrict__ in, float* __restrict__ out,
                             W7 wt, int total) {
    int idx = blockIdx.x * blockDim.x + threadIdx.x;
    if (idx >= total) return;
    int w = idx % DIM;
    int h = (idx / DIM) % DIM;
    int d = (idx / (DIM * DIM)) % DIM;
    const float* base = in + (idx - w - h * DIM - d * DIM * DIM);
    float acc = 0.f;
    for (int a = 0; a < 7; ++a) {
        int dd = d + a - 3;
        if (dd < 0 || dd >= DIM) continue;
        for (int bme = 0; bme < 7; ++bme) {
            int hh = h + bme - 3;
            if (hh < 0 || hh >= DIM) continue;
            float wab = wt.w[a] * wt.w[bme];
            for (int c = 0; c < 7; ++c) {
                int ww = w + c - 3;
                if (ww < 0 || ww >= DIM) continue;
                acc += wab * wt.w[c] * base[(dd * DIM + hh) * DIM + ww];
            }
        }
    }
    out[idx] = acc;
}

extern "C" void kernel_launch(void* const* d_in, const int* in_sizes, int n_in,
                              void* d_out, int out_size, void* d_ws, size_t ws_size,
                              hipStream_t stream) {
    const float* x = (const float*)d_in[0];
    float* out = (float*)d_out;
    const int total = out_size;            // 2*2*160^3 = 16,384,000

    W7 wt;
    double s = 0.0;
    for (int i = 0; i < 7; ++i) {
        double v = exp(-((i - 3) * (i - 3)) / 8.0);
        wt.w[i] = (float)v;
        s += v;
    }
    for (int i = 0; i < 7; ++i) wt.w[i] = (float)(wt.w[i] / s);

    if (ws_size >= (size_t)total * sizeof(float)) {
        float* tmp = (float*)d_ws;
        const int nc = total / (DIM * DIM * DIM);          // 4
        const int blocksWH = nc * DIM * (DIM / HT);        // 6400
        blur_wh<<<blocksWH, 256, 0, stream>>>(x, tmp, wt);
        const int total4 = total / 4;
        blur_d4<<<(total4 + 255) / 256, 256, 0, stream>>>(
            (const float4*)tmp, (float4*)out, wt, total4);
    } else {
        blur3d_naive<<<(total + 255) / 256, 256, 0, stream>>>(x, out, wt, total);
    }
}

// Round 3
// 53.412 us; speedup vs baseline: 4.4094x; 2.0271x over previous
//
#include <hip/hip_runtime.h>
#include <math.h>

#define DIM 160
#define HT 32            // h-tile rows per WH block
#define ROWS (HT + 6)    // 38 rows incl. halo
#define LROW 168         // padded LDS row: 4 zero | 160 data | 4 zero
#define CHUNK 20         // d-slices per D-march thread
#define SLAB4 (DIM * DIM / 4)   // 6400 float4 per d-slice

struct W7 { float w[7]; };

// ---- Fused W+H blur of one (d-slice, h-strip): x -> ws ----
__global__ __launch_bounds__(512) void blur_wh(const float* __restrict__ in,
                                               float* __restrict__ out, W7 wt) {
    __shared__ float inL[ROWS * LROW];   // padded raw rows (25.5 KB)
    __shared__ float tmpL[ROWS * DIM];   // W-blurred rows  (24.3 KB)

    const int tilesH = DIM / HT;                 // 5
    int b   = blockIdx.x;
    int nc  = b / (DIM * tilesH);
    int rem = b % (DIM * tilesH);
    int d   = rem / tilesH;
    int h0  = (rem % tilesH) * HT;
    int tid = threadIdx.x;

    const float* img = in + ((size_t)nc * DIM + d) * (DIM * DIM);

    // stage 1: load 38 rows (zero outside H range) into padded LDS, float4
    for (int i = tid; i < ROWS * 40; i += 512) {
        int r = i / 40, c = i % 40;
        int h = h0 - 3 + r;
        float4 v = make_float4(0.f, 0.f, 0.f, 0.f);
        if (h >= 0 && h < DIM) v = ((const float4*)(img + h * DIM))[c];
        ((float4*)(inL + r * LROW + 4))[c] = v;
    }
    // zero the guard columns (w-padding => branch-free W loop)
    for (int i = tid; i < ROWS * 2; i += 512) {
        int r = i / 2, side = i % 2;
        ((float4*)(inL + r * LROW + (side ? 164 : 0)))[0] =
            make_float4(0.f, 0.f, 0.f, 0.f);
    }
    __syncthreads();

    // stage 2: W-blur (branch-free thanks to guards)
    for (int i = tid; i < ROWS * DIM; i += 512) {
        int r = i / DIM, w = i % DIM;
        const float* p = inL + r * LROW + w + 1;   // = &in[w-3] in padded coords
        float acc = 0.f;
#pragma unroll
        for (int j = 0; j < 7; ++j) acc += wt.w[j] * p[j];
        tmpL[r * DIM + w] = acc;
    }
    __syncthreads();

    // stage 3: H-blur + float4 store
    float* orow = out + ((size_t)nc * DIM + d) * (DIM * DIM) + (size_t)h0 * DIM;
    for (int i = tid; i < HT * 40; i += 512) {
        int hh = i / 40, c = i % 40;
        float4 acc = make_float4(0.f, 0.f, 0.f, 0.f);
#pragma unroll
        for (int j = 0; j < 7; ++j) {
            float4 t = ((const float4*)(tmpL + (hh + j) * DIM))[c];
            float wj = wt.w[j];
            acc.x += wj * t.x; acc.y += wj * t.y;
            acc.z += wj * t.z; acc.w += wj * t.w;
        }
        ((float4*)(orow + hh * DIM))[c] = acc;
    }
}

// ---- D blur, register sliding window: ws -> out ----
// Each thread owns one float4 slab position and marches CHUNK d-slices,
// reading each input slice exactly once (7-slot register ring).
__global__ __launch_bounds__(256) void blur_dm(const float4* __restrict__ in,
                                               float4* __restrict__ out, W7 wt) {
    const int sblocks = SLAB4 / 256;             // 25
    const int nchunks = DIM / CHUNK;             // 8
    int b     = blockIdx.x;
    int sblk  = b % sblocks;
    int chunk = (b / sblocks) % nchunks;
    int ch    = b / (sblocks * nchunks);
    int s4    = sblk * 256 + threadIdx.x;
    int d0    = chunk * CHUNK;
    const size_t base = (size_t)ch * DIM * SLAB4;

    const float4 z4 = make_float4(0.f, 0.f, 0.f, 0.f);
    float4 win[7];
#pragma unroll
    for (int j = 0; j < 6; ++j) {
        int dd = d0 - 3 + j;
        win[j] = (dd >= 0 && dd < DIM) ? in[base + (size_t)dd * SLAB4 + s4] : z4;
    }
#pragma unroll
    for (int k = 0; k < CHUNK; ++k) {
        int dd = d0 + k + 3;
        win[(k + 6) % 7] = (dd < DIM) ? in[base + (size_t)dd * SLAB4 + s4] : z4;
        float4 acc = make_float4(0.f, 0.f, 0.f, 0.f);
#pragma unroll
        for (int j = 0; j < 7; ++j) {
            float wj = wt.w[j];
            float4 v = win[(k + j) % 7];
            acc.x += wj * v.x; acc.y += wj * v.y;
            acc.z += wj * v.z; acc.w += wj * v.w;
        }
        out[base + (size_t)(d0 + k) * SLAB4 + s4] = acc;
    }
}

// ---- Fallback: direct 343-tap (only if ws too small) ----
__global__ void blur3d_naive(const float* __restrict__ in, float* __restrict__ out,
                             W7 wt, int total) {
    int idx = blockIdx.x * blockDim.x + threadIdx.x;
    if (idx >= total) return;
    int w = idx % DIM;
    int h = (idx / DIM) % DIM;
    int d = (idx / (DIM * DIM)) % DIM;
    const float* base = in + (idx - w - h * DIM - d * DIM * DIM);
    float acc = 0.f;
    for (int a = 0; a < 7; ++a) {
        int dd = d + a - 3;
        if (dd < 0 || dd >= DIM) continue;
        for (int bme = 0; bme < 7; ++bme) {
            int hh = h + bme - 3;
            if (hh < 0 || hh >= DIM) continue;
            float wab = wt.w[a] * wt.w[bme];
            for (int c = 0; c < 7; ++c) {
                int ww = w + c - 3;
                if (ww < 0 || ww >= DIM) continue;
                acc += wab * wt.w[c] * base[(dd * DIM + hh) * DIM + ww];
            }
        }
    }
    out[idx] = acc;
}

extern "C" void kernel_launch(void* const* d_in, const int* in_sizes, int n_in,
                              void* d_out, int out_size, void* d_ws, size_t ws_size,
                              hipStream_t stream) {
    const float* x = (const float*)d_in[0];
    float* out = (float*)d_out;
    const int total = out_size;            // 2*2*160^3 = 16,384,000

    W7 wt;
    double s = 0.0;
    for (int i = 0; i < 7; ++i) {
        double v = exp(-((i - 3) * (i - 3)) / 8.0);
        wt.w[i] = (float)v;
        s += v;
    }
    for (int i = 0; i < 7; ++i) wt.w[i] = (float)(wt.w[i] / s);

    if (ws_size >= (size_t)total * sizeof(float)) {
        float* tmp = (float*)d_ws;
        const int nc = total / (DIM * DIM * DIM);          // 4
        const int blocksWH = nc * DIM * (DIM / HT);        // 3200
        blur_wh<<<blocksWH, 512, 0, stream>>>(x, tmp, wt);
        const int blocksD = nc * (DIM / CHUNK) * (SLAB4 / 256);  // 800
        blur_dm<<<blocksD, 256, 0, stream>>>(
            (const float4*)tmp, (float4*)out, wt);
    } else {
        blur3d_naive<<<(total + 255) / 256, 256, 0, stream>>>(x, out, wt, total);
    }
}